// Round 1
// baseline (2010.718 us; speedup 1.0000x reference)
//
#include <hip/hip_runtime.h>
#include <math.h>

// ---------------------------------------------------------------------------
// Problem constants: B=256, T=256, LEN=256 (audio 64 | vision 64 | text 128)
// text proj: [65536,768]@[768,512]; fusion: RANK=24, EXT=513
// ---------------------------------------------------------------------------

__device__ __forceinline__ float sigf(float x) { return 1.0f / (1.0f + __expf(-x)); }
__device__ __forceinline__ float tanhf2(float x) { return 2.0f / (1.0f + __expf(-2.0f * x)) - 1.0f; }

// ------------------- text input projection GEMM (fp32) ---------------------
// Y[M=65536, N=512] = X[M, K=768] @ W[N, K]^T   (bias added in LSTM kernel)
__global__ __launch_bounds__(256) void gemm_text_k(const float* __restrict__ X,
                                                   const float* __restrict__ W,
                                                   float* __restrict__ Y) {
  const int K = 768, N = 512;
  __shared__ __align__(16) float As[16][68];
  __shared__ __align__(16) float Bs[16][68];
  const int n0 = blockIdx.x * 64;
  const int m0 = blockIdx.y * 64;
  const int tid = threadIdx.x;
  const int tx = tid & 15, ty = tid >> 4;          // compute mapping: 4x4 per thread
  const int kk4 = (tid & 3) << 2, rr = tid >> 2;   // staging mapping: row rr, k off kk4
  float acc[4][4] = {};
  const float* Xp = X + (size_t)(m0 + rr) * K + kk4;
  const float* Wp = W + (size_t)(n0 + rr) * K + kk4;
  for (int k0 = 0; k0 < K; k0 += 16) {
    const float4 xa = *(const float4*)(Xp + k0);
    const float4 wb = *(const float4*)(Wp + k0);
    __syncthreads();
    As[kk4 + 0][rr] = xa.x; As[kk4 + 1][rr] = xa.y;
    As[kk4 + 2][rr] = xa.z; As[kk4 + 3][rr] = xa.w;
    Bs[kk4 + 0][rr] = wb.x; Bs[kk4 + 1][rr] = wb.y;
    Bs[kk4 + 2][rr] = wb.z; Bs[kk4 + 3][rr] = wb.w;
    __syncthreads();
#pragma unroll
    for (int kk = 0; kk < 16; kk++) {
      const float4 av = *(const float4*)&As[kk][ty << 2];
      const float4 bv = *(const float4*)&Bs[kk][tx << 2];
      const float a4[4] = {av.x, av.y, av.z, av.w};
      const float b4[4] = {bv.x, bv.y, bv.z, bv.w};
#pragma unroll
      for (int i = 0; i < 4; i++)
#pragma unroll
        for (int j = 0; j < 4; j++) acc[i][j] += a4[i] * b4[j];
    }
  }
#pragma unroll
  for (int i = 0; i < 4; i++) {
    float4 o;
    o.x = acc[i][0]; o.y = acc[i][1]; o.z = acc[i][2]; o.w = acc[i][3];
    *(float4*)&Y[(size_t)(m0 + (ty << 2) + i) * N + n0 + (tx << 2)] = o;
  }
}

// ----------------------------- text LSTM (H=128) ---------------------------
// 1 block per batch element, 512 threads = one per gate row.
// Whh row (128 f) in VGPRs; h broadcast from LDS; writes h into z cols 128..255
__global__ __launch_bounds__(512) void lstm_text_k(const float* __restrict__ xproj,
                                                   const float* __restrict__ Whh,
                                                   const float* __restrict__ bias,
                                                   float* __restrict__ z) {
  const int H = 128, G = 512;
  __shared__ __align__(16) float h_s[128];
  __shared__ float g_s[512];
  const int tid = threadIdx.x;
  const int b = blockIdx.x;
  float4 w[32];
  const float4* wp = (const float4*)(Whh + (size_t)tid * H);
#pragma unroll
  for (int j = 0; j < 32; j++) w[j] = wp[j];
  const float bv = bias[tid];
  float c = 0.0f;
  if (tid < H) h_s[tid] = 0.0f;
  __syncthreads();
  const float* xrow = xproj + (size_t)b * 256 * G;
  float* zrow = z + (size_t)b * 256 * 256 + 128;
  float xv = xrow[tid];
  for (int t = 0; t < 256; t++) {
    int tn = t + 1; if (tn > 255) tn = 255;
    const float xnext = xrow[tn * G + tid];   // prefetch next step's xproj
    float g = xv + bv;
    const float4* h4 = (const float4*)h_s;
#pragma unroll
    for (int j = 0; j < 32; j++) {
      const float4 hv = h4[j];
      g += w[j].x * hv.x + w[j].y * hv.y + w[j].z * hv.z + w[j].w * hv.w;
    }
    const float act = ((tid >> 7) == 2) ? tanhf2(g) : sigf(g);  // gate order i,f,g,o
    g_s[tid] = act;
    __syncthreads();
    if (tid < H) {
      const float i_s = g_s[tid], f_s = g_s[H + tid];
      const float gg = g_s[2 * H + tid], o_s = g_s[3 * H + tid];
      c = f_s * c + i_s * gg;
      const float h = o_s * tanhf2(c);
      h_s[tid] = h;
      zrow[t * 256 + tid] = h;
    }
    __syncthreads();
    xv = xnext;
  }
}

// ------------------- audio / vision LSTM (H=64, fused input proj) ----------
// Wih row (KIN f) + Whh row (64 f) in VGPRs; x_t double-buffered in LDS.
template <int H, int KIN, int COFF>
__global__ __launch_bounds__(256) void lstm_small_k(const float* __restrict__ x,
                                                    const float* __restrict__ Wih,
                                                    const float* __restrict__ Whh,
                                                    const float* __restrict__ bias,
                                                    float* __restrict__ z) {
  __shared__ __align__(16) float h_s[H];
  __shared__ float g_s[4 * H];
  __shared__ float x_s[2][KIN];
  const int tid = threadIdx.x;
  const int b = blockIdx.x;
  float wih[KIN];
  {
    const float* p = Wih + (size_t)tid * KIN;
#pragma unroll
    for (int k = 0; k < KIN; k++) wih[k] = p[k];
  }
  float4 whh[H / 4];
  {
    const float4* p = (const float4*)(Whh + (size_t)tid * H);
#pragma unroll
    for (int j = 0; j < H / 4; j++) whh[j] = p[j];
  }
  const float bv = bias[tid];
  float c = 0.0f;
  if (tid < H) h_s[tid] = 0.0f;
  if (tid < KIN) x_s[0][tid] = x[(size_t)b * 256 * KIN + tid];
  __syncthreads();
  for (int t = 0; t < 256; t++) {
    const float* xs = x_s[t & 1];
    float g = bv;
#pragma unroll
    for (int k = 0; k < KIN; k++) g += wih[k] * xs[k];
    const float4* h4 = (const float4*)h_s;
#pragma unroll
    for (int j = 0; j < H / 4; j++) {
      const float4 hv = h4[j];
      g += whh[j].x * hv.x + whh[j].y * hv.y + whh[j].z * hv.z + whh[j].w * hv.w;
    }
    const float act = ((tid / H) == 2) ? tanhf2(g) : sigf(g);
    g_s[tid] = act;
    if (t < 255 && tid < KIN) x_s[(t + 1) & 1][tid] = x[((size_t)b * 256 + t + 1) * KIN + tid];
    __syncthreads();
    if (tid < H) {
      const float i_s = g_s[tid], f_s = g_s[H + tid];
      const float gg = g_s[2 * H + tid], o_s = g_s[3 * H + tid];
      c = f_s * c + i_s * gg;
      const float h = o_s * tanhf2(c);
      h_s[tid] = h;
      z[((size_t)b * 256 + t) * 256 + COFF + tid] = h;
    }
    __syncthreads();
  }
}

// ------------------------------- fusion ------------------------------------
// block = (b, 32-row t-tile). z tile staged transposed in LDS: zs[k][row].
// thread (dg in 0..23, rg in 0..7): 4 rows x 3 partial dots (a, bb_t, bb_{t+1}).
// Accumulates sum_t sum_r fw_r*a_r*bb_r and sum z^2 -> atomics into workspace.
__global__ __launch_bounds__(192) void fusion_k(const float* __restrict__ z,
                                                const float* __restrict__ W1,
                                                const float* __restrict__ b1,
                                                const float* __restrict__ W2,
                                                const float* __restrict__ b2,
                                                const float* __restrict__ fw,
                                                float* __restrict__ s_acc,
                                                float* __restrict__ sumsq) {
  __shared__ __align__(16) float zs[256 * 36];  // [k][row], stride 36, rows 0..32
  __shared__ float red[8];
  const int tid = threadIdx.x;
  const int b = blockIdx.x >> 3;
  const int t0 = (blockIdx.x & 7) * 32;
  const float* zb = z + (size_t)b * 65536;
  float sq = 0.0f;
  for (int idx = tid; idx < 33 * 256; idx += 192) {
    const int row = idx >> 8, k = idx & 255;
    int t = t0 + row; if (t >= 256) t -= 256;   // wrap for the +1 row of last tile
    const float v = zb[t * 256 + k];
    zs[k * 36 + row] = v;
    if (row < 32) sq += v * v;                  // Frobenius sum (rows counted once)
  }
  __syncthreads();
  const int dg = tid >> 3;   // rank 0..23
  const int rg = tid & 7;    // row group 0..7 (4 rows each)
  const float* w1p = W1 + dg * 256;
  const float* w2p = W2 + dg * 513;
  float aa[4] = {}, ab1[4] = {}, ab2[4] = {};
#pragma unroll 4
  for (int k = 0; k < 256; k++) {
    const float w1v = w1p[k];
    const float w21 = w2p[1 + k];
    const float w22 = w2p[257 + k];
    const float* zr = &zs[k * 36 + (rg << 2)];
    const float4 za = *(const float4*)zr;
    const float z4 = zr[4];
    aa[0]  += za.x * w1v; aa[1]  += za.y * w1v; aa[2]  += za.z * w1v; aa[3]  += za.w * w1v;
    ab1[0] += za.x * w21; ab1[1] += za.y * w21; ab1[2] += za.z * w21; ab1[3] += za.w * w21;
    ab2[0] += za.y * w22; ab2[1] += za.z * w22; ab2[2] += za.w * w22; ab2[3] += z4   * w22;
  }
  const float b1v = b1[dg];
  const float b2v = b2[dg] + w2p[0];   // + W2[r,0] * ones
  const float fwv = fw[dg];
  float s = 0.0f;
#pragma unroll
  for (int i = 0; i < 4; i++) {
    const float a  = aa[i] + b1v;
    const float bb = ab1[i] + ab2[i] + b2v;
    s += a * bb;
  }
  s *= fwv;
#pragma unroll
  for (int off = 32; off > 0; off >>= 1) {
    s  += __shfl_down(s, off);
    sq += __shfl_down(sq, off);
  }
  const int wid = tid >> 6;
  if ((tid & 63) == 0) { red[wid * 2] = s; red[wid * 2 + 1] = sq; }
  __syncthreads();
  if (tid == 0) {
    atomicAdd(&s_acc[b], red[0] + red[2] + red[4]);
    atomicAdd(&sumsq[b], red[1] + red[3] + red[5]);
  }
}

// ------------------------------- epilogue ----------------------------------
__global__ __launch_bounds__(256) void final_k(const float* __restrict__ s_acc,
                                               const float* __restrict__ sumsq,
                                               float* __restrict__ out) {
  __shared__ float red[4];
  const int tid = threadIdx.x;
  out[tid] = s_acc[tid] * (1.0f / 256.0f);       // mean over T
  float sq = sqrtf(sumsq[tid]);
#pragma unroll
  for (int off = 32; off > 0; off >>= 1) sq += __shfl_down(sq, off);
  if ((tid & 63) == 0) red[tid >> 6] = sq;
  __syncthreads();
  if (tid == 0) out[256] = (red[0] + red[1] + red[2] + red[3]) * (1.0f / 256.0f);
}

// ---------------------------------------------------------------------------
extern "C" void kernel_launch(void* const* d_in, const int* in_sizes, int n_in,
                              void* d_out, int out_size, void* d_ws, size_t ws_size,
                              hipStream_t stream) {
  const float* text   = (const float*)d_in[0];
  const float* audio  = (const float*)d_in[1];
  const float* vision = (const float*)d_in[2];
  const float* Wih_t  = (const float*)d_in[3];
  const float* Whh_t  = (const float*)d_in[4];
  const float* b_t    = (const float*)d_in[5];
  const float* Wih_a  = (const float*)d_in[6];
  const float* Whh_a  = (const float*)d_in[7];
  const float* b_a    = (const float*)d_in[8];
  const float* Wih_v  = (const float*)d_in[9];
  const float* Whh_v  = (const float*)d_in[10];
  const float* b_v    = (const float*)d_in[11];
  const float* W1     = (const float*)d_in[12];
  const float* b1     = (const float*)d_in[13];
  const float* W2     = (const float*)d_in[14];
  const float* b2     = (const float*)d_in[15];
  const float* fw     = (const float*)d_in[16];

  float* ws    = (float*)d_ws;
  float* xproj = ws;                              // 65536*512 f32 (134 MB)
  float* z     = ws + (size_t)65536 * 512;        // 65536*256 f32 (67 MB)
  float* s_acc = z + (size_t)65536 * 256;         // 256 f32
  float* sumsq = s_acc + 256;                     // 256 f32

  hipMemsetAsync(s_acc, 0, 512 * sizeof(float), stream);

  gemm_text_k<<<dim3(8, 1024), 256, 0, stream>>>(text, Wih_t, xproj);
  lstm_small_k<64, 74, 0><<<256, 256, 0, stream>>>(audio, Wih_a, Whh_a, b_a, z);
  lstm_small_k<64, 35, 64><<<256, 256, 0, stream>>>(vision, Wih_v, Whh_v, b_v, z);
  lstm_text_k<<<256, 512, 0, stream>>>(xproj, Whh_t, b_t, z);
  fusion_k<<<2048, 192, 0, stream>>>(z, W1, b1, W2, b2, fw, s_acc, sumsq);
  final_k<<<1, 256, 0, stream>>>(s_acc, sumsq, (float*)d_out);
}

// Round 2
// 1190.401 us; speedup vs baseline: 1.6891x; 1.6891x over previous
//
#include <hip/hip_runtime.h>
#include <math.h>

// ---------------------------------------------------------------------------
// B=256, T=256, LEN=256 (audio 64 | vision 64 | text 128)
// text proj: [65536,768]@[768,512]^T via bf16 MFMA; fusion RANK=24, EXT=513
// ---------------------------------------------------------------------------

typedef short bf16x8 __attribute__((ext_vector_type(8)));
typedef float f32x4 __attribute__((ext_vector_type(4)));

__device__ __forceinline__ float sigf(float x) { return 1.0f / (1.0f + __expf(-x)); }
__device__ __forceinline__ float tanhf2(float x) { return 2.0f / (1.0f + __expf(-2.0f * x)) - 1.0f; }

__device__ __forceinline__ unsigned int f2bf(float f) {  // RNE truncate to bf16
  unsigned int u = __float_as_uint(f);
  u += 0x7FFFu + ((u >> 16) & 1u);
  return u >> 16;
}
__device__ __forceinline__ unsigned int pk2bf(float lo, float hi) {
  return f2bf(lo) | (f2bf(hi) << 16);
}

// ---------------------- W (Wih_t) fp32 -> bf16 pre-convert ------------------
__global__ __launch_bounds__(256) void convert_w_k(const float* __restrict__ W,
                                                   unsigned short* __restrict__ W16) {
  const int i = blockIdx.x * 256 + threadIdx.x;     // 98304 float4s total
  const float4 v = ((const float4*)W)[i];
  uint2 o;
  o.x = pk2bf(v.x, v.y);
  o.y = pk2bf(v.z, v.w);
  ((uint2*)W16)[i] = o;
}

// -------------------- text input projection GEMM (bf16 MFMA) ----------------
// Y[M=65536, N=512] = X[M, K=768] @ W16[N, K]^T ; fp32 accumulate.
#define SA 72  // LDS row stride in bf16 elements (144 B = 36 dwords -> <=2-way bank alias)
__global__ __launch_bounds__(256) void gemm_mfma_k(const float* __restrict__ X,
                                                   const unsigned short* __restrict__ W16,
                                                   float* __restrict__ Y) {
  const int K = 768, N = 512;
  __shared__ __align__(16) unsigned short As[128 * SA];
  __shared__ __align__(16) unsigned short Bs[128 * SA];
  // XCD-aware swizzle: 4 consecutive blocks on one XCD share the same A tile.
  const unsigned int lin = blockIdx.x;
  const int m_idx = (int)((lin >> 5) * 8 + (lin & 7));   // 0..511
  const int n_idx = (int)((lin >> 3) & 3);               // 0..3
  const int m0 = m_idx * 128, n0 = n_idx * 128;
  const int tid = threadIdx.x;
  const int srow = tid >> 1, shalf = tid & 1;            // staging: half-row per thread
  const int wave = tid >> 6, lane = tid & 63;
  const int wr = wave >> 1, wc = wave & 1;               // 2x2 wave grid (64x64 each)
  const int lm = lane & 15, lq = lane >> 4;

  const float*          Xp = X   + (size_t)(m0 + srow) * K + shalf * 32;
  const unsigned short* Wp = W16 + (size_t)(n0 + srow) * K + shalf * 32;
  unsigned short* As_w = &As[srow * SA + shalf * 32];
  unsigned short* Bs_w = &Bs[srow * SA + shalf * 32];

  f32x4 acc[4][4];
#pragma unroll
  for (int i = 0; i < 4; i++)
#pragma unroll
    for (int j = 0; j < 4; j++) acc[i][j] = (f32x4){0.f, 0.f, 0.f, 0.f};

  for (int k0 = 0; k0 < K; k0 += 64) {
    // global loads (A: 32 fp32, B: 32 bf16 per thread)
    float4 a[8];
    const float4* xp4 = (const float4*)(Xp + k0);
#pragma unroll
    for (int i = 0; i < 8; i++) a[i] = xp4[i];
    uint4 bvv[4];
    const uint4* wp4 = (const uint4*)(Wp + k0);
#pragma unroll
    for (int i = 0; i < 4; i++) bvv[i] = wp4[i];

    __syncthreads();   // previous compute done before overwriting LDS
    uint4* bw = (uint4*)Bs_w;
#pragma unroll
    for (int i = 0; i < 4; i++) bw[i] = bvv[i];
    uint4* aw = (uint4*)As_w;
#pragma unroll
    for (int i = 0; i < 4; i++) {
      uint4 o;
      o.x = pk2bf(a[2 * i].x, a[2 * i].y);
      o.y = pk2bf(a[2 * i].z, a[2 * i].w);
      o.z = pk2bf(a[2 * i + 1].x, a[2 * i + 1].y);
      o.w = pk2bf(a[2 * i + 1].z, a[2 * i + 1].w);
      aw[i] = o;
    }
    __syncthreads();

#pragma unroll
    for (int ks = 0; ks < 64; ks += 32) {
      bf16x8 af[4], bfv[4];
#pragma unroll
      for (int mt = 0; mt < 4; mt++)
        af[mt] = *(const bf16x8*)&As[(wr * 64 + mt * 16 + lm) * SA + ks + lq * 8];
#pragma unroll
      for (int nt = 0; nt < 4; nt++)
        bfv[nt] = *(const bf16x8*)&Bs[(wc * 64 + nt * 16 + lm) * SA + ks + lq * 8];
#pragma unroll
      for (int mt = 0; mt < 4; mt++)
#pragma unroll
        for (int nt = 0; nt < 4; nt++)
          acc[mt][nt] = __builtin_amdgcn_mfma_f32_16x16x32_bf16(af[mt], bfv[nt], acc[mt][nt], 0, 0, 0);
    }
  }
  // epilogue: C/D layout col=lane&15, row=(lane>>4)*4+reg
#pragma unroll
  for (int mt = 0; mt < 4; mt++) {
#pragma unroll
    for (int nt = 0; nt < 4; nt++) {
      const int row0 = m0 + wr * 64 + mt * 16 + lq * 4;
      const int col = n0 + wc * 64 + nt * 16 + lm;
#pragma unroll
      for (int r = 0; r < 4; r++) Y[(size_t)(row0 + r) * N + col] = acc[mt][nt][r];
    }
  }
}

// ----------------------------- text LSTM (H=128) ---------------------------
__global__ __launch_bounds__(512) void lstm_text_k(const float* __restrict__ xproj,
                                                   const float* __restrict__ Whh,
                                                   const float* __restrict__ bias,
                                                   float* __restrict__ z) {
  const int H = 128, G = 512;
  __shared__ __align__(16) float h_s[128];
  __shared__ float g_s[512];
  const int tid = threadIdx.x;
  const int b = blockIdx.x;
  float4 w[32];
  const float4* wp = (const float4*)(Whh + (size_t)tid * H);
#pragma unroll
  for (int j = 0; j < 32; j++) w[j] = wp[j];
  const float bv = bias[tid];
  float c = 0.0f;
  if (tid < H) h_s[tid] = 0.0f;
  __syncthreads();
  const float* xrow = xproj + (size_t)b * 256 * G;
  float* zrow = z + (size_t)b * 256 * 256 + 128;
  float xv = xrow[tid];
  for (int t = 0; t < 256; t++) {
    int tn = t + 1; if (tn > 255) tn = 255;
    const float xnext = xrow[tn * G + tid];   // prefetch next step
    float g0 = xv + bv, g1 = 0.f, g2 = 0.f, g3 = 0.f;  // 4 accumulators: break dep chain
    const float4* h4 = (const float4*)h_s;
#pragma unroll
    for (int j = 0; j < 32; j += 4) {
      float4 hv0 = h4[j], hv1 = h4[j + 1], hv2 = h4[j + 2], hv3 = h4[j + 3];
      g0 += w[j].x * hv0.x + w[j].y * hv0.y + w[j].z * hv0.z + w[j].w * hv0.w;
      g1 += w[j+1].x * hv1.x + w[j+1].y * hv1.y + w[j+1].z * hv1.z + w[j+1].w * hv1.w;
      g2 += w[j+2].x * hv2.x + w[j+2].y * hv2.y + w[j+2].z * hv2.z + w[j+2].w * hv2.w;
      g3 += w[j+3].x * hv3.x + w[j+3].y * hv3.y + w[j+3].z * hv3.z + w[j+3].w * hv3.w;
    }
    const float g = (g0 + g1) + (g2 + g3);
    const float act = ((tid >> 7) == 2) ? tanhf2(g) : sigf(g);  // gate order i,f,g,o
    g_s[tid] = act;
    __syncthreads();
    if (tid < H) {
      const float i_s = g_s[tid], f_s = g_s[H + tid];
      const float gg = g_s[2 * H + tid], o_s = g_s[3 * H + tid];
      c = f_s * c + i_s * gg;
      const float h = o_s * tanhf2(c);
      h_s[tid] = h;
      zrow[t * 256 + tid] = h;
    }
    __syncthreads();
    xv = xnext;
  }
}

// ---------------- audio / vision LSTM (H=64, fused input proj) -------------
template <int H, int KIN, int COFF>
__device__ __forceinline__ void lstm_body(const float* __restrict__ x,
                                          const float* __restrict__ Wih,
                                          const float* __restrict__ Whh,
                                          const float* __restrict__ bias,
                                          float* __restrict__ z, int b, int tid) {
  __shared__ __align__(16) float h_s[H];
  __shared__ float g_s[4 * H];
  __shared__ float x_s[2][KIN];
  float wih[KIN];
  {
    const float* p = Wih + (size_t)tid * KIN;
#pragma unroll
    for (int k = 0; k < KIN; k++) wih[k] = p[k];
  }
  float4 whh[H / 4];
  {
    const float4* p = (const float4*)(Whh + (size_t)tid * H);
#pragma unroll
    for (int j = 0; j < H / 4; j++) whh[j] = p[j];
  }
  const float bv = bias[tid];
  float c = 0.0f;
  if (tid < H) h_s[tid] = 0.0f;
  if (tid < KIN) x_s[0][tid] = x[(size_t)b * 256 * KIN + tid];
  __syncthreads();
  for (int t = 0; t < 256; t++) {
    const float* xs = x_s[t & 1];
    float g0 = bv, g1 = 0.f, g2 = 0.f, g3 = 0.f;
#pragma unroll
    for (int k = 0; k + 4 <= KIN; k += 4) {
      g0 += wih[k] * xs[k];
      g1 += wih[k + 1] * xs[k + 1];
      g2 += wih[k + 2] * xs[k + 2];
      g3 += wih[k + 3] * xs[k + 3];
    }
#pragma unroll
    for (int k = KIN & ~3; k < KIN; k++) g0 += wih[k] * xs[k];
    const float4* h4 = (const float4*)h_s;
#pragma unroll
    for (int j = 0; j < H / 4; j += 4) {
      float4 hv0 = h4[j], hv1 = h4[j + 1], hv2 = h4[j + 2], hv3 = h4[j + 3];
      g0 += whh[j].x * hv0.x + whh[j].y * hv0.y + whh[j].z * hv0.z + whh[j].w * hv0.w;
      g1 += whh[j+1].x * hv1.x + whh[j+1].y * hv1.y + whh[j+1].z * hv1.z + whh[j+1].w * hv1.w;
      g2 += whh[j+2].x * hv2.x + whh[j+2].y * hv2.y + whh[j+2].z * hv2.z + whh[j+2].w * hv2.w;
      g3 += whh[j+3].x * hv3.x + whh[j+3].y * hv3.y + whh[j+3].z * hv3.z + whh[j+3].w * hv3.w;
    }
    const float g = (g0 + g1) + (g2 + g3);
    const float act = ((tid / H) == 2) ? tanhf2(g) : sigf(g);
    g_s[tid] = act;
    if (t < 255 && tid < KIN) x_s[(t + 1) & 1][tid] = x[((size_t)b * 256 + t + 1) * KIN + tid];
    __syncthreads();
    if (tid < H) {
      const float i_s = g_s[tid], f_s = g_s[H + tid];
      const float gg = g_s[2 * H + tid], o_s = g_s[3 * H + tid];
      c = f_s * c + i_s * gg;
      const float h = o_s * tanhf2(c);
      h_s[tid] = h;
      z[((size_t)b * 256 + t) * 256 + COFF + tid] = h;
    }
    __syncthreads();
  }
}

__global__ __launch_bounds__(256) void lstm_av_k(const float* __restrict__ audio,
                                                 const float* __restrict__ Wih_a,
                                                 const float* __restrict__ Whh_a,
                                                 const float* __restrict__ b_a,
                                                 const float* __restrict__ vision,
                                                 const float* __restrict__ Wih_v,
                                                 const float* __restrict__ Whh_v,
                                                 const float* __restrict__ b_v,
                                                 float* __restrict__ z) {
  const int tid = threadIdx.x;
  if (blockIdx.x < 256)
    lstm_body<64, 74, 0>(audio, Wih_a, Whh_a, b_a, z, blockIdx.x, tid);
  else
    lstm_body<64, 35, 64>(vision, Wih_v, Whh_v, b_v, z, blockIdx.x - 256, tid);
}

// ------------------------------- fusion ------------------------------------
__global__ __launch_bounds__(192) void fusion_k(const float* __restrict__ z,
                                                const float* __restrict__ W1,
                                                const float* __restrict__ b1,
                                                const float* __restrict__ W2,
                                                const float* __restrict__ b2,
                                                const float* __restrict__ fw,
                                                float* __restrict__ s_acc,
                                                float* __restrict__ sumsq) {
  __shared__ __align__(16) float zs[256 * 36];  // [k][row], stride 36
  __shared__ float red[8];
  const int tid = threadIdx.x;
  const int b = blockIdx.x >> 3;
  const int t0 = (blockIdx.x & 7) * 32;
  const float* zb = z + (size_t)b * 65536;
  float sq = 0.0f;
  for (int idx = tid; idx < 33 * 256; idx += 192) {
    const int row = idx >> 8, k = idx & 255;
    int t = t0 + row; if (t >= 256) t -= 256;
    const float v = zb[t * 256 + k];
    zs[k * 36 + row] = v;
    if (row < 32) sq += v * v;
  }
  __syncthreads();
  const int dg = tid >> 3;   // rank 0..23
  const int rg = tid & 7;    // row group (4 rows each)
  const float* w1p = W1 + dg * 256;
  const float* w2p = W2 + dg * 513;
  float aa[4] = {}, ab1[4] = {}, ab2[4] = {};
#pragma unroll 4
  for (int k = 0; k < 256; k++) {
    const float w1v = w1p[k];
    const float w21 = w2p[1 + k];
    const float w22 = w2p[257 + k];
    const float* zr = &zs[k * 36 + (rg << 2)];
    const float4 za = *(const float4*)zr;
    const float z4 = zr[4];
    aa[0]  += za.x * w1v; aa[1]  += za.y * w1v; aa[2]  += za.z * w1v; aa[3]  += za.w * w1v;
    ab1[0] += za.x * w21; ab1[1] += za.y * w21; ab1[2] += za.z * w21; ab1[3] += za.w * w21;
    ab2[0] += za.y * w22; ab2[1] += za.z * w22; ab2[2] += za.w * w22; ab2[3] += z4   * w22;
  }
  const float b1v = b1[dg];
  const float b2v = b2[dg] + w2p[0];
  const float fwv = fw[dg];
  float s = 0.0f;
#pragma unroll
  for (int i = 0; i < 4; i++) {
    const float a  = aa[i] + b1v;
    const float bb = ab1[i] + ab2[i] + b2v;
    s += a * bb;
  }
  s *= fwv;
#pragma unroll
  for (int off = 32; off > 0; off >>= 1) {
    s  += __shfl_down(s, off);
    sq += __shfl_down(sq, off);
  }
  const int wid = tid >> 6;
  if ((tid & 63) == 0) { red[wid * 2] = s; red[wid * 2 + 1] = sq; }
  __syncthreads();
  if (tid == 0) {
    atomicAdd(&s_acc[b], red[0] + red[2] + red[4]);
    atomicAdd(&sumsq[b], red[1] + red[3] + red[5]);
  }
}

// ------------------------------- epilogue ----------------------------------
__global__ __launch_bounds__(256) void final_k(const float* __restrict__ s_acc,
                                               const float* __restrict__ sumsq,
                                               float* __restrict__ out) {
  __shared__ float red[4];
  const int tid = threadIdx.x;
  out[tid] = s_acc[tid] * (1.0f / 256.0f);
  float sq = sqrtf(sumsq[tid]);
#pragma unroll
  for (int off = 32; off > 0; off >>= 1) sq += __shfl_down(sq, off);
  if ((tid & 63) == 0) red[tid >> 6] = sq;
  __syncthreads();
  if (tid == 0) out[256] = (red[0] + red[1] + red[2] + red[3]) * (1.0f / 256.0f);
}

// ---------------------------------------------------------------------------
extern "C" void kernel_launch(void* const* d_in, const int* in_sizes, int n_in,
                              void* d_out, int out_size, void* d_ws, size_t ws_size,
                              hipStream_t stream) {
  const float* text   = (const float*)d_in[0];
  const float* audio  = (const float*)d_in[1];
  const float* vision = (const float*)d_in[2];
  const float* Wih_t  = (const float*)d_in[3];
  const float* Whh_t  = (const float*)d_in[4];
  const float* b_t    = (const float*)d_in[5];
  const float* Wih_a  = (const float*)d_in[6];
  const float* Whh_a  = (const float*)d_in[7];
  const float* b_a    = (const float*)d_in[8];
  const float* Wih_v  = (const float*)d_in[9];
  const float* Whh_v  = (const float*)d_in[10];
  const float* b_v    = (const float*)d_in[11];
  const float* W1     = (const float*)d_in[12];
  const float* b1     = (const float*)d_in[13];
  const float* W2     = (const float*)d_in[14];
  const float* b2     = (const float*)d_in[15];
  const float* fw     = (const float*)d_in[16];

  float* ws    = (float*)d_ws;
  float* xproj = ws;                              // 65536*512 f32 (134 MB)
  float* z     = ws + (size_t)65536 * 512;        // 65536*256 f32 (67 MB)
  float* s_acc = z + (size_t)65536 * 256;         // 256 f32
  float* sumsq = s_acc + 256;                     // 256 f32
  // W16 lives in the z region: gemm reads it before any LSTM writes z.
  unsigned short* W16 = (unsigned short*)z;

  hipMemsetAsync(s_acc, 0, 512 * sizeof(float), stream);

  convert_w_k<<<384, 256, 0, stream>>>(Wih_t, W16);
  gemm_mfma_k<<<2048, 256, 0, stream>>>(text, W16, xproj);
  lstm_av_k<<<512, 256, 0, stream>>>(audio, Wih_a, Whh_a, b_a,
                                     vision, Wih_v, Whh_v, b_v, z);
  lstm_text_k<<<256, 512, 0, stream>>>(xproj, Whh_t, b_t, z);
  fusion_k<<<2048, 192, 0, stream>>>(z, W1, b1, W2, b2, fw, s_acc, sumsq);
  final_k<<<1, 256, 0, stream>>>(s_acc, sumsq, (float*)d_out);
}

// Round 4
// 1070.303 us; speedup vs baseline: 1.8786x; 1.1122x over previous
//
#include <hip/hip_runtime.h>
#include <math.h>

// ---------------------------------------------------------------------------
// B=256, T=256, LEN=256 (audio 64 | vision 64 | text 128), RANK=24, EXT=513
// Strategy: all input projections as bf16 MFMA GEMMs (bias folded, bf16 out);
// recurrences batched over B with MFMA (16 batch rows x 4H gates per block),
// one barrier/step; z stored bf16.
// ---------------------------------------------------------------------------

typedef unsigned short ushortT;
typedef short bf16x8 __attribute__((ext_vector_type(8)));
typedef float f32x4 __attribute__((ext_vector_type(4)));

__device__ __forceinline__ float sigf(float x) { return 1.0f / (1.0f + __expf(-x)); }
__device__ __forceinline__ float tanhf2(float x) { return 2.0f / (1.0f + __expf(-2.0f * x)) - 1.0f; }

__device__ __forceinline__ unsigned int f2bf(float f) {  // RNE to bf16
  unsigned int u = __float_as_uint(f);
  u += 0x7FFFu + ((u >> 16) & 1u);
  return u >> 16;
}
__device__ __forceinline__ unsigned int pk2bf(float lo, float hi) {
  return f2bf(lo) | (f2bf(hi) << 16);
}
__device__ __forceinline__ float bf2f(ushortT u) {
  return __uint_as_float(((unsigned int)u) << 16);
}

// ------------------ generic fp32 -> bf16 convert (+K-pad) -------------------
template <int KP, int KIN>
__global__ __launch_bounds__(256) void pad_cvt_k(const float* __restrict__ src,
                                                 ushortT* __restrict__ dst, int total) {
  const int i = blockIdx.x * 256 + threadIdx.x;
  if (i >= total) return;
  if constexpr (KP == KIN) {
    dst[i] = (ushortT)f2bf(src[i]);
  } else {
    const int row = i / KP, c = i - row * KP;
    dst[i] = (c < KIN) ? (ushortT)f2bf(src[(size_t)row * KIN + c]) : (ushortT)0;
  }
}

// -------------------- text input projection GEMM (bf16 MFMA) ----------------
// Y16[M=65536, 512] = bf16( X[M,768] @ W16[512,768]^T + bias )
#define SA 72
__global__ __launch_bounds__(256) void gemm_mfma_k(const float* __restrict__ X,
                                                   const ushortT* __restrict__ W16,
                                                   const float* __restrict__ bias,
                                                   ushortT* __restrict__ Y16) {
  const int K = 768, N = 512;
  __shared__ __align__(16) ushortT As[128 * SA];
  __shared__ __align__(16) ushortT Bs[128 * SA];
  const unsigned int lin = blockIdx.x;
  const int m_idx = (int)((lin >> 5) * 8 + (lin & 7));
  const int n_idx = (int)((lin >> 3) & 3);
  const int m0 = m_idx * 128, n0 = n_idx * 128;
  const int tid = threadIdx.x;
  const int srow = tid >> 1, shalf = tid & 1;
  const int wave = tid >> 6, lane = tid & 63;
  const int wr = wave >> 1, wc = wave & 1;
  const int lm = lane & 15, lq = lane >> 4;

  const float*   Xp = X   + (size_t)(m0 + srow) * K + shalf * 32;
  const ushortT* Wp = W16 + (size_t)(n0 + srow) * K + shalf * 32;
  ushortT* As_w = &As[srow * SA + shalf * 32];
  ushortT* Bs_w = &Bs[srow * SA + shalf * 32];

  f32x4 acc[4][4];
#pragma unroll
  for (int i = 0; i < 4; i++)
#pragma unroll
    for (int j = 0; j < 4; j++) acc[i][j] = (f32x4){0.f, 0.f, 0.f, 0.f};

  for (int k0 = 0; k0 < K; k0 += 64) {
    float4 a[8];
    const float4* xp4 = (const float4*)(Xp + k0);
#pragma unroll
    for (int i = 0; i < 8; i++) a[i] = xp4[i];
    uint4 bvv[4];
    const uint4* wp4 = (const uint4*)(Wp + k0);
#pragma unroll
    for (int i = 0; i < 4; i++) bvv[i] = wp4[i];

    __syncthreads();
    uint4* bw = (uint4*)Bs_w;
#pragma unroll
    for (int i = 0; i < 4; i++) bw[i] = bvv[i];
    uint4* aw = (uint4*)As_w;
#pragma unroll
    for (int i = 0; i < 4; i++) {
      uint4 o;
      o.x = pk2bf(a[2 * i].x, a[2 * i].y);
      o.y = pk2bf(a[2 * i].z, a[2 * i].w);
      o.z = pk2bf(a[2 * i + 1].x, a[2 * i + 1].y);
      o.w = pk2bf(a[2 * i + 1].z, a[2 * i + 1].w);
      aw[i] = o;
    }
    __syncthreads();

#pragma unroll
    for (int ks = 0; ks < 64; ks += 32) {
      bf16x8 af[4], bfv[4];
#pragma unroll
      for (int mt = 0; mt < 4; mt++)
        af[mt] = *(const bf16x8*)&As[(wr * 64 + mt * 16 + lm) * SA + ks + lq * 8];
#pragma unroll
      for (int nt = 0; nt < 4; nt++)
        bfv[nt] = *(const bf16x8*)&Bs[(wc * 64 + nt * 16 + lm) * SA + ks + lq * 8];
#pragma unroll
      for (int mt = 0; mt < 4; mt++)
#pragma unroll
        for (int nt = 0; nt < 4; nt++)
          acc[mt][nt] = __builtin_amdgcn_mfma_f32_16x16x32_bf16(af[mt], bfv[nt], acc[mt][nt], 0, 0, 0);
    }
  }
  float biasv[4];
#pragma unroll
  for (int nt = 0; nt < 4; nt++) biasv[nt] = bias[n0 + wc * 64 + nt * 16 + lm];
#pragma unroll
  for (int mt = 0; mt < 4; mt++) {
#pragma unroll
    for (int nt = 0; nt < 4; nt++) {
      const int row0 = m0 + wr * 64 + mt * 16 + lq * 4;
      const int col = n0 + wc * 64 + nt * 16 + lm;
#pragma unroll
      for (int r = 0; r < 4; r++)
        Y16[(size_t)(row0 + r) * N + col] = (ushortT)f2bf(acc[mt][nt][r] + biasv[nt]);
    }
  }
}

// ------------- audio/vision input projection (small-K bf16 MFMA) ------------
// Y16[65536, 256] = bf16( A16[65536,KP] @ B16[256,KP]^T + bias )
template <int KP>
__global__ __launch_bounds__(256) void gemm_xp_k(const ushortT* __restrict__ A16,
                                                 const ushortT* __restrict__ B16,
                                                 const float* __restrict__ bias,
                                                 ushortT* __restrict__ Y16) {
  constexpr int SB = KP + 8;
  __shared__ __align__(16) ushortT As[128 * SB];
  __shared__ __align__(16) ushortT Bs[128 * SB];
  const int n0 = blockIdx.x * 128;
  const int m0 = blockIdx.y * 128;
  const int tid = threadIdx.x;
  const int srow = tid >> 1, shalf = tid & 1;
  const int wave = tid >> 6, lane = tid & 63;
  const int wr = wave >> 1, wc = wave & 1;
  const int lm = lane & 15, lq = lane >> 4;

  const uint4* ap = (const uint4*)(A16 + (size_t)(m0 + srow) * KP + shalf * (KP / 2));
  const uint4* bp = (const uint4*)(B16 + (size_t)(n0 + srow) * KP + shalf * (KP / 2));
  uint4* aw = (uint4*)&As[srow * SB + shalf * (KP / 2)];
  uint4* bw = (uint4*)&Bs[srow * SB + shalf * (KP / 2)];
#pragma unroll
  for (int i = 0; i < KP / 16; i++) { aw[i] = ap[i]; bw[i] = bp[i]; }
  __syncthreads();

  constexpr int KC = KP / 32;
  f32x4 acc[4][4];
#pragma unroll
  for (int i = 0; i < 4; i++)
#pragma unroll
    for (int j = 0; j < 4; j++) acc[i][j] = (f32x4){0.f, 0.f, 0.f, 0.f};
#pragma unroll
  for (int ks = 0; ks < KC; ks++) {
    bf16x8 af[4], bfv[4];
#pragma unroll
    for (int mt = 0; mt < 4; mt++)
      af[mt] = *(const bf16x8*)&As[(wr * 64 + mt * 16 + lm) * SB + ks * 32 + lq * 8];
#pragma unroll
    for (int nt = 0; nt < 4; nt++)
      bfv[nt] = *(const bf16x8*)&Bs[(wc * 64 + nt * 16 + lm) * SB + ks * 32 + lq * 8];
#pragma unroll
    for (int mt = 0; mt < 4; mt++)
#pragma unroll
      for (int nt = 0; nt < 4; nt++)
        acc[mt][nt] = __builtin_amdgcn_mfma_f32_16x16x32_bf16(af[mt], bfv[nt], acc[mt][nt], 0, 0, 0);
  }
  float biasv[4];
#pragma unroll
  for (int nt = 0; nt < 4; nt++) biasv[nt] = bias[n0 + wc * 64 + nt * 16 + lm];
#pragma unroll
  for (int mt = 0; mt < 4; mt++) {
#pragma unroll
    for (int nt = 0; nt < 4; nt++) {
      const int row0 = m0 + wr * 64 + mt * 16 + lq * 4;
      const int col = n0 + wc * 64 + nt * 16 + lm;
#pragma unroll
      for (int r = 0; r < 4; r++)
        Y16[(size_t)(row0 + r) * 256 + col] = (ushortT)f2bf(acc[mt][nt][r] + biasv[nt]);
    }
  }
}

// --------------------- batched-MFMA LSTM recurrence -------------------------
// Block: 512 thr = 8 waves. Wave owns a 16-wide h slice of all 4 gates for a
// 16-batch group. h exchanged via double-buffered LDS; 1 barrier/step.
template <int H, int NG, int COFF>
__device__ __forceinline__ void recur_impl(const ushortT* __restrict__ xp,   // [B*T][4H] bf16, bias folded
                                           const ushortT* __restrict__ Whh, // [4H][H] bf16
                                           ushortT* __restrict__ z,         // [B*T][256] bf16
                                           int bblk) {
  constexpr int KC = H / 32;
  constexpr int WPG = H / 16;   // waves per batch group
  constexpr int C4H = 4 * H;
  constexpr int HP = H + 8;
  constexpr int ROWS = 16 * NG;
  __shared__ ushortT hbuf[2][ROWS * HP];
  const int tid = threadIdx.x;
  const int wave = tid >> 6, lane = tid & 63;
  const int bgrp = wave / WPG, s = wave % WPG;
  const int lm = lane & 15, lq = lane >> 4;
  const int b0 = bblk * ROWS + bgrp * 16;

  bf16x8 bw[4][KC];
#pragma unroll
  for (int g = 0; g < 4; g++)
#pragma unroll
    for (int kc = 0; kc < KC; kc++) {
      const int n = g * H + s * 16 + lm;
      bw[g][kc] = *(const bf16x8*)(Whh + (size_t)n * H + kc * 32 + lq * 8);
    }
  for (int i = tid; i < ROWS * HP; i += 512) hbuf[0][i] = 0;

  unsigned int voff[4][4];
  ushortT xpv[4][4];
#pragma unroll
  for (int g = 0; g < 4; g++)
#pragma unroll
    for (int r = 0; r < 4; r++)
      voff[g][r] = (unsigned)(b0 + lq * 4 + r) * 256u * C4H + g * H + s * 16 + lm;
#pragma unroll
  for (int g = 0; g < 4; g++)
#pragma unroll
    for (int r = 0; r < 4; r++) { xpv[g][r] = xp[voff[g][r]]; voff[g][r] += C4H; }

  float cst[4] = {0.f, 0.f, 0.f, 0.f};
  unsigned int zoff[4];
#pragma unroll
  for (int r = 0; r < 4; r++)
    zoff[r] = (unsigned)(b0 + lq * 4 + r) * 256u * 256u + COFF + s * 16 + lm;

  __syncthreads();

  for (int t = 0; t < 256; t++) {
    const int cur = t & 1;
    bf16x8 af[KC];
    const ushortT* hb = &hbuf[cur][(bgrp * 16 + lm) * HP];
#pragma unroll
    for (int kc = 0; kc < KC; kc++)
      af[kc] = *(const bf16x8*)(hb + kc * 32 + lq * 8);
    f32x4 acc[4];
#pragma unroll
    for (int g = 0; g < 4; g++) acc[g] = (f32x4){0.f, 0.f, 0.f, 0.f};
#pragma unroll
    for (int kc = 0; kc < KC; kc++)
#pragma unroll
      for (int g = 0; g < 4; g++)
        acc[g] = __builtin_amdgcn_mfma_f32_16x16x32_bf16(af[kc], bw[g][kc], acc[g], 0, 0, 0);
    float gv[4][4];
#pragma unroll
    for (int g = 0; g < 4; g++)
#pragma unroll
      for (int r = 0; r < 4; r++) gv[g][r] = acc[g][r] + bf2f(xpv[g][r]);
    if (t < 255) {  // prefetch next step's xproj (lands during act+barrier+MFMA)
#pragma unroll
      for (int g = 0; g < 4; g++)
#pragma unroll
        for (int r = 0; r < 4; r++) { xpv[g][r] = xp[voff[g][r]]; voff[g][r] += C4H; }
    }
    ushortT* hn = &hbuf[cur ^ 1][0];
#pragma unroll
    for (int r = 0; r < 4; r++) {
      const float iv = sigf(gv[0][r]);
      const float fv = sigf(gv[1][r]);
      const float gg = tanhf2(gv[2][r]);
      const float ov = sigf(gv[3][r]);
      cst[r] = fv * cst[r] + iv * gg;
      const float hv = ov * tanhf2(cst[r]);
      const ushortT h16 = (ushortT)f2bf(hv);
      hn[(bgrp * 16 + lq * 4 + r) * HP + s * 16 + lm] = h16;
      z[zoff[r]] = h16;
      zoff[r] += 256;
    }
    __syncthreads();
  }
}

__global__ __launch_bounds__(512) void recur_k(const ushortT* __restrict__ xpt,
                                               const ushortT* __restrict__ xpa,
                                               const ushortT* __restrict__ xpv_,
                                               const ushortT* __restrict__ Wt,
                                               const ushortT* __restrict__ Wa,
                                               const ushortT* __restrict__ Wv,
                                               ushortT* __restrict__ z) {
  const int bid = blockIdx.x;
  if (bid < 16) recur_impl<128, 1, 128>(xpt, Wt, z, bid);
  else if (bid < 24) recur_impl<64, 2, 0>(xpa, Wa, z, bid - 16);
  else recur_impl<64, 2, 64>(xpv_, Wv, z, bid - 24);
}

// ------------------------------- fusion ------------------------------------
__global__ __launch_bounds__(192) void fusion_k(const ushortT* __restrict__ z,
                                                const float* __restrict__ W1,
                                                const float* __restrict__ b1,
                                                const float* __restrict__ W2,
                                                const float* __restrict__ b2,
                                                const float* __restrict__ fw,
                                                float* __restrict__ s_acc,
                                                float* __restrict__ sumsq) {
  __shared__ __align__(16) float zs[256 * 36];
  __shared__ float red[8];
  const int tid = threadIdx.x;
  const int b = blockIdx.x >> 3;
  const int t0 = (blockIdx.x & 7) * 32;
  const ushortT* zb = z + (size_t)b * 65536;
  float sq = 0.0f;
  for (int idx = tid; idx < 33 * 256; idx += 192) {
    const int row = idx >> 8, k = idx & 255;
    int t = t0 + row; if (t >= 256) t -= 256;
    const float v = bf2f(zb[t * 256 + k]);
    zs[k * 36 + row] = v;
    if (row < 32) sq += v * v;
  }
  __syncthreads();
  const int dg = tid >> 3;
  const int rg = tid & 7;
  const float* w1p = W1 + dg * 256;
  const float* w2p = W2 + dg * 513;
  float aa[4] = {}, ab1[4] = {}, ab2[4] = {};
#pragma unroll 4
  for (int k = 0; k < 256; k++) {
    const float w1v = w1p[k];
    const float w21 = w2p[1 + k];
    const float w22 = w2p[257 + k];
    const float* zr = &zs[k * 36 + (rg << 2)];
    const float4 za = *(const float4*)zr;
    const float z4 = zr[4];
    aa[0]  += za.x * w1v; aa[1]  += za.y * w1v; aa[2]  += za.z * w1v; aa[3]  += za.w * w1v;
    ab1[0] += za.x * w21; ab1[1] += za.y * w21; ab1[2] += za.z * w21; ab1[3] += za.w * w21;
    ab2[0] += za.y * w22; ab2[1] += za.z * w22; ab2[2] += za.w * w22; ab2[3] += z4   * w22;
  }
  const float b1v = b1[dg];
  const float b2v = b2[dg] + w2p[0];
  const float fwv = fw[dg];
  float s = 0.0f;
#pragma unroll
  for (int i = 0; i < 4; i++) {
    const float a  = aa[i] + b1v;
    const float bb = ab1[i] + ab2[i] + b2v;
    s += a * bb;
  }
  s *= fwv;
#pragma unroll
  for (int off = 32; off > 0; off >>= 1) {
    s  += __shfl_down(s, off);
    sq += __shfl_down(sq, off);
  }
  const int wid = tid >> 6;
  if ((tid & 63) == 0) { red[wid * 2] = s; red[wid * 2 + 1] = sq; }
  __syncthreads();
  if (tid == 0) {
    atomicAdd(&s_acc[b], red[0] + red[2] + red[4]);
    atomicAdd(&sumsq[b], red[1] + red[3] + red[5]);
  }
}

// ------------------------------- epilogue ----------------------------------
__global__ __launch_bounds__(256) void final_k(const float* __restrict__ s_acc,
                                               const float* __restrict__ sumsq,
                                               float* __restrict__ out) {
  __shared__ float red[4];
  const int tid = threadIdx.x;
  out[tid] = s_acc[tid] * (1.0f / 256.0f);
  float sq = sqrtf(sumsq[tid]);
#pragma unroll
  for (int off = 32; off > 0; off >>= 1) sq += __shfl_down(sq, off);
  if ((tid & 63) == 0) red[tid >> 6] = sq;
  __syncthreads();
  if (tid == 0) out[256] = (red[0] + red[1] + red[2] + red[3]) * (1.0f / 256.0f);
}

// ---------------------------------------------------------------------------
extern "C" void kernel_launch(void* const* d_in, const int* in_sizes, int n_in,
                              void* d_out, int out_size, void* d_ws, size_t ws_size,
                              hipStream_t stream) {
  const float* text   = (const float*)d_in[0];
  const float* audio  = (const float*)d_in[1];
  const float* vision = (const float*)d_in[2];
  const float* Wih_t  = (const float*)d_in[3];
  const float* Whh_t  = (const float*)d_in[4];
  const float* b_t    = (const float*)d_in[5];
  const float* Wih_a  = (const float*)d_in[6];
  const float* Whh_a  = (const float*)d_in[7];
  const float* b_a    = (const float*)d_in[8];
  const float* Wih_v  = (const float*)d_in[9];
  const float* Whh_v  = (const float*)d_in[10];
  const float* b_v    = (const float*)d_in[11];
  const float* W1     = (const float*)d_in[12];
  const float* b1     = (const float*)d_in[13];
  const float* W2     = (const float*)d_in[14];
  const float* b2     = (const float*)d_in[15];
  const float* fw     = (const float*)d_in[16];

  // workspace layout (bf16 elems unless noted); total ~168 MB
  ushortT* xpt = (ushortT*)d_ws;               // 65536*512
  ushortT* xpa = xpt + (size_t)33554432;       // 65536*256
  ushortT* xpv = xpa + (size_t)16777216;       // 65536*256
  ushortT* z16 = xpv + (size_t)16777216;       // 65536*256
  float* s_acc = (float*)(z16 + (size_t)16777216);  // 256 f32
  float* sumsq = s_acc + 256;                       // 256 f32
  ushortT* WhhT16 = (ushortT*)(sumsq + 256);   // 512*128
  ushortT* WhhA16 = WhhT16 + 65536;            // 256*64
  ushortT* WhhV16 = WhhA16 + 16384;            // 256*64
  // scratch aliased into z16 (fully consumed before recur_k writes z):
  ushortT* A16a  = z16;                        // 65536*96
  ushortT* A16v  = A16a + (size_t)6291456;     // 65536*64
  ushortT* Wt768 = A16v + (size_t)4194304;     // 512*768
  ushortT* WA16  = Wt768 + 393216;             // 256*96
  ushortT* WV16  = WA16 + 24576;               // 256*64

  hipMemsetAsync(s_acc, 0, 512 * sizeof(float), stream);

  pad_cvt_k<768, 768><<<1536, 256, 0, stream>>>(Wih_t, Wt768, 512 * 768);
  pad_cvt_k<128, 128><<<256, 256, 0, stream>>>(Whh_t, WhhT16, 512 * 128);
  pad_cvt_k<64, 64><<<64, 256, 0, stream>>>(Whh_a, WhhA16, 256 * 64);
  pad_cvt_k<64, 64><<<64, 256, 0, stream>>>(Whh_v, WhhV16, 256 * 64);
  pad_cvt_k<96, 74><<<96, 256, 0, stream>>>(Wih_a, WA16, 256 * 96);
  pad_cvt_k<64, 35><<<64, 256, 0, stream>>>(Wih_v, WV16, 256 * 64);
  pad_cvt_k<96, 74><<<24576, 256, 0, stream>>>(audio, A16a, 65536 * 96);
  pad_cvt_k<64, 35><<<16384, 256, 0, stream>>>(vision, A16v, 65536 * 64);

  gemm_mfma_k<<<2048, 256, 0, stream>>>(text, Wt768, b_t, xpt);
  gemm_xp_k<96><<<dim3(2, 512), 256, 0, stream>>>(A16a, WA16, b_a, xpa);
  gemm_xp_k<64><<<dim3(2, 512), 256, 0, stream>>>(A16v, WV16, b_v, xpv);
  recur_k<<<32, 512, 0, stream>>>(xpt, xpa, xpv, WhhT16, WhhA16, WhhV16, z16);
  fusion_k<<<2048, 192, 0, stream>>>(z16, W1, b1, W2, b2, fw, s_acc, sumsq);
  final_k<<<1, 256, 0, stream>>>(s_acc, sumsq, (float*)d_out);
}

// Round 5
// 954.859 us; speedup vs baseline: 2.1058x; 1.1209x over previous
//
#include <hip/hip_runtime.h>
#include <math.h>

// ---------------------------------------------------------------------------
// B=256, T=256, LEN=256 (audio 64 | vision 64 | text 128), RANK=24, EXT=513
// ---------------------------------------------------------------------------

typedef unsigned short ushortT;
typedef short bf16x8 __attribute__((ext_vector_type(8)));
typedef float f32x4 __attribute__((ext_vector_type(4)));

__device__ __forceinline__ unsigned int f2bf(float f) {  // RNE to bf16
  unsigned int u = __float_as_uint(f);
  u += 0x7FFFu + ((u >> 16) & 1u);
  return u >> 16;
}
__device__ __forceinline__ unsigned int pk2bf(float lo, float hi) {
  return f2bf(lo) | (f2bf(hi) << 16);
}
__device__ __forceinline__ float bf2f(ushortT u) {
  return __uint_as_float(((unsigned int)u) << 16);
}

// ------------------ generic fp32 -> bf16 convert (+K-pad) -------------------
template <int KP, int KIN>
__global__ __launch_bounds__(256) void pad_cvt_k(const float* __restrict__ src,
                                                 ushortT* __restrict__ dst, int total) {
  const int i = blockIdx.x * 256 + threadIdx.x;
  if (i >= total) return;
  if constexpr (KP == KIN) {
    dst[i] = (ushortT)f2bf(src[i]);
  } else {
    const int row = i / KP, c = i - row * KP;
    dst[i] = (c < KIN) ? (ushortT)f2bf(src[(size_t)row * KIN + c]) : (ushortT)0;
  }
}

// ---------------- text input projection GEMM (bf16 MFMA, 128x256) -----------
// Y16[M=65536, 512] = bf16( X[M,768] @ W16[512,768]^T + bias )
#define SA2 40  // LDS row stride (BK=32 + 8 pad) -> <=2-way bank alias on frag reads
__global__ __launch_bounds__(512) void gemm_text2_k(const float* __restrict__ X,
                                                    const ushortT* __restrict__ W16,
                                                    const float* __restrict__ bias,
                                                    ushortT* __restrict__ Y16) {
  const int K = 768, N = 512;
  __shared__ __align__(16) ushortT As[128 * SA2];
  __shared__ __align__(16) ushortT Bs[256 * SA2];
  // n-siblings (same m-tile) at dispatch stride 8 -> same XCD -> A L2 reuse.
  const unsigned int lin = blockIdx.x;
  const int gb = (int)(lin >> 4), rb = (int)(lin & 15);
  const int m0 = (gb * 8 + (rb & 7)) * 128;
  const int n0 = (rb >> 3) * 256;
  const int tid = threadIdx.x;
  const int wave = tid >> 6, lane = tid & 63;
  const int wr = wave >> 2, wc = wave & 3;          // 2x4 wave grid (64x64 each)
  const int lm = lane & 15, lq = lane >> 4;
  const int arow = tid >> 2, aq = (tid & 3) * 8;    // A staging: 8 fp32/thread
  const int brow = tid >> 1, bq = (tid & 1) * 16;   // B staging: 16 bf16/thread

  const float*   Xp = X + (size_t)(m0 + arow) * K + aq;
  const ushortT* Wp = W16 + (size_t)(n0 + brow) * K + bq;
  uint4* As_w = (uint4*)&As[arow * SA2 + aq];
  uint4* Bs_w = (uint4*)&Bs[brow * SA2 + bq];

  f32x4 acc[4][4];
#pragma unroll
  for (int i = 0; i < 4; i++)
#pragma unroll
    for (int j = 0; j < 4; j++) acc[i][j] = (f32x4){0.f, 0.f, 0.f, 0.f};

  for (int k0 = 0; k0 < K; k0 += 32) {
    const float4 a0 = *(const float4*)(Xp + k0);
    const float4 a1 = *(const float4*)(Xp + k0 + 4);
    const uint4 b0v = *(const uint4*)(Wp + k0);
    const uint4 b1v = *(const uint4*)(Wp + k0 + 8);
    __syncthreads();
    uint4 ao;
    ao.x = pk2bf(a0.x, a0.y); ao.y = pk2bf(a0.z, a0.w);
    ao.z = pk2bf(a1.x, a1.y); ao.w = pk2bf(a1.z, a1.w);
    As_w[0] = ao;
    Bs_w[0] = b0v;
    Bs_w[1] = b1v;
    __syncthreads();
    bf16x8 af[4], bfv[4];
#pragma unroll
    for (int mt = 0; mt < 4; mt++)
      af[mt] = *(const bf16x8*)&As[(wr * 64 + mt * 16 + lm) * SA2 + lq * 8];
#pragma unroll
    for (int nt = 0; nt < 4; nt++)
      bfv[nt] = *(const bf16x8*)&Bs[(wc * 64 + nt * 16 + lm) * SA2 + lq * 8];
#pragma unroll
    for (int mt = 0; mt < 4; mt++)
#pragma unroll
      for (int nt = 0; nt < 4; nt++)
        acc[mt][nt] = __builtin_amdgcn_mfma_f32_16x16x32_bf16(af[mt], bfv[nt], acc[mt][nt], 0, 0, 0);
  }
  float biasv[4];
#pragma unroll
  for (int nt = 0; nt < 4; nt++) biasv[nt] = bias[n0 + wc * 64 + nt * 16 + lm];
#pragma unroll
  for (int mt = 0; mt < 4; mt++) {
#pragma unroll
    for (int nt = 0; nt < 4; nt++) {
      const int row0 = m0 + wr * 64 + mt * 16 + lq * 4;
      const int col = n0 + wc * 64 + nt * 16 + lm;
#pragma unroll
      for (int r = 0; r < 4; r++)
        Y16[(size_t)(row0 + r) * N + col] = (ushortT)f2bf(acc[mt][nt][r] + biasv[nt]);
    }
  }
}

// ------------- audio/vision input projection (small-K bf16 MFMA) ------------
template <int KP>
__global__ __launch_bounds__(256) void gemm_xp_k(const ushortT* __restrict__ A16,
                                                 const ushortT* __restrict__ B16,
                                                 const float* __restrict__ bias,
                                                 ushortT* __restrict__ Y16) {
  constexpr int SB = KP + 8;
  __shared__ __align__(16) ushortT As[128 * SB];
  __shared__ __align__(16) ushortT Bs[128 * SB];
  const int n0 = blockIdx.x * 128;
  const int m0 = blockIdx.y * 128;
  const int tid = threadIdx.x;
  const int srow = tid >> 1, shalf = tid & 1;
  const int wave = tid >> 6, lane = tid & 63;
  const int wr = wave >> 1, wc = wave & 1;
  const int lm = lane & 15, lq = lane >> 4;

  const uint4* ap = (const uint4*)(A16 + (size_t)(m0 + srow) * KP + shalf * (KP / 2));
  const uint4* bp = (const uint4*)(B16 + (size_t)(n0 + srow) * KP + shalf * (KP / 2));
  uint4* aw = (uint4*)&As[srow * SB + shalf * (KP / 2)];
  uint4* bw = (uint4*)&Bs[srow * SB + shalf * (KP / 2)];
#pragma unroll
  for (int i = 0; i < KP / 16; i++) { aw[i] = ap[i]; bw[i] = bp[i]; }
  __syncthreads();

  constexpr int KC = KP / 32;
  f32x4 acc[4][4];
#pragma unroll
  for (int i = 0; i < 4; i++)
#pragma unroll
    for (int j = 0; j < 4; j++) acc[i][j] = (f32x4){0.f, 0.f, 0.f, 0.f};
#pragma unroll
  for (int ks = 0; ks < KC; ks++) {
    bf16x8 af[4], bfv[4];
#pragma unroll
    for (int mt = 0; mt < 4; mt++)
      af[mt] = *(const bf16x8*)&As[(wr * 64 + mt * 16 + lm) * SB + ks * 32 + lq * 8];
#pragma unroll
    for (int nt = 0; nt < 4; nt++)
      bfv[nt] = *(const bf16x8*)&Bs[(wc * 64 + nt * 16 + lm) * SB + ks * 32 + lq * 8];
#pragma unroll
    for (int mt = 0; mt < 4; mt++)
#pragma unroll
      for (int nt = 0; nt < 4; nt++)
        acc[mt][nt] = __builtin_amdgcn_mfma_f32_16x16x32_bf16(af[mt], bfv[nt], acc[mt][nt], 0, 0, 0);
  }
  float biasv[4];
#pragma unroll
  for (int nt = 0; nt < 4; nt++) biasv[nt] = bias[n0 + wc * 64 + nt * 16 + lm];
#pragma unroll
  for (int mt = 0; mt < 4; mt++) {
#pragma unroll
    for (int nt = 0; nt < 4; nt++) {
      const int row0 = m0 + wr * 64 + mt * 16 + lq * 4;
      const int col = n0 + wc * 64 + nt * 16 + lm;
#pragma unroll
      for (int r = 0; r < 4; r++)
        Y16[(size_t)(row0 + r) * 256 + col] = (ushortT)f2bf(acc[mt][nt][r] + biasv[nt]);
    }
  }
}

// --------------------- batched-MFMA LSTM recurrence (v2) --------------------
// Block = 256 thr = 4 waves, 16 batch rows. Wave s owns cols [s*SL, s*SL+SL)
// of each gate. xp staged per-step into LDS (coalesced); h kept in a 6-deep
// LDS ring, flushed to z every 4 steps with wide stores. 1 barrier/step.
template <int H, int COFF>
__device__ __forceinline__ void recur_impl2(const ushortT* __restrict__ xp,   // [B*T][4H]
                                            const ushortT* __restrict__ Whh, // [4H][H]
                                            ushortT* __restrict__ z,         // [B*T][256]
                                            int bblk, char* smem_) {
  constexpr int SL = H / 4;          // cols per gate per wave
  constexpr int NU = SL / 16;        // 16-col tiles per gate per wave
  constexpr int KC = H / 32;
  constexpr int C4H = 4 * H;
  constexpr int HP = H + 8;          // h-ring row stride
  constexpr int XP = C4H + 8;        // xp-stage row stride
  constexpr int RING = 6;
  constexpr int NCH4 = C4H / 128;    // uint4 chunks per staging thread
  constexpr int CRB = H / 8;         // 16B runs per z row
  ushortT* hbuf = (ushortT*)smem_;                 // [RING][16][HP]
  ushortT* xps = hbuf + RING * 16 * HP;            // [2][16][XP]
  const int tid = threadIdx.x;
  const int s = tid >> 6, lane = tid & 63;
  const int lm = lane & 15, lq = lane >> 4;
  const int b0 = bblk * 16;

  bf16x8 bw[4][NU][KC];
#pragma unroll
  for (int g = 0; g < 4; g++)
#pragma unroll
    for (int u = 0; u < NU; u++)
#pragma unroll
      for (int kc = 0; kc < KC; kc++) {
        const int n = g * H + s * SL + u * 16 + lm;
        bw[g][u][kc] = *(const bf16x8*)(Whh + (size_t)n * H + kc * 32 + lq * 8);
      }
  for (int i = tid; i < 16 * HP; i += 256) hbuf[(RING - 1) * 16 * HP + i] = 0;
  const int srow = tid >> 4, sch = tid & 15;
  {  // stage xp for t=0 into xps[0]
    const uint4* src = (const uint4*)(xp + ((size_t)(b0 + srow) * 256) * C4H + sch * (C4H / 16));
    uint4* dst = (uint4*)&xps[srow * XP + sch * (C4H / 16)];
#pragma unroll
    for (int i = 0; i < NCH4; i++) dst[i] = src[i];
  }
  float cst[NU][4];
#pragma unroll
  for (int u = 0; u < NU; u++)
#pragma unroll
    for (int r = 0; r < 4; r++) cst[u][r] = 0.f;
  __syncthreads();

  for (int t = 0; t < 256; t++) {
    // ---- flush h-ring to z (4 rows, wide stores), off the critical path ----
    if (t >= 4 && (t & 3) == 0) {
      const int t0 = t - 4;
#pragma unroll
      for (int i = 0; i < (64 * CRB) / 256; i++) {
        const int q = i * 256 + tid;
        const int m = q / (4 * CRB), j = (q / CRB) & 3, cr = q % CRB;
        const uint4 v = *(const uint4*)&hbuf[((t0 + j) % RING) * 16 * HP + m * HP + cr * 8];
        *(uint4*)&z[((size_t)(b0 + m) * 256 + t0 + j) * 256 + COFF + cr * 8] = v;
      }
    }
    // ---- issue coalesced staging loads for step t+1 (drained at barrier) ---
    const int tn = (t < 255) ? t + 1 : 255;
    uint4 sv[NCH4];
    {
      const uint4* src = (const uint4*)(xp + ((size_t)(b0 + srow) * 256 + tn) * C4H + sch * (C4H / 16));
#pragma unroll
      for (int i = 0; i < NCH4; i++) sv[i] = src[i];
    }
    // ---- gate GEMM ----
    const ushortT* hb = &hbuf[((t + RING - 1) % RING) * 16 * HP + lm * HP];
    bf16x8 af[KC];
#pragma unroll
    for (int kc = 0; kc < KC; kc++) af[kc] = *(const bf16x8*)(hb + kc * 32 + lq * 8);
    f32x4 acc[4][NU];
#pragma unroll
    for (int g = 0; g < 4; g++)
#pragma unroll
      for (int u = 0; u < NU; u++) acc[g][u] = (f32x4){0.f, 0.f, 0.f, 0.f};
#pragma unroll
    for (int kc = 0; kc < KC; kc++)
#pragma unroll
      for (int g = 0; g < 4; g++)
#pragma unroll
        for (int u = 0; u < NU; u++)
          acc[g][u] = __builtin_amdgcn_mfma_f32_16x16x32_bf16(af[kc], bw[g][u][kc], acc[g][u], 0, 0, 0);
    // ---- activations (fused: 5 exp + 2 rcp per h) + h write ----
    const ushortT* xb = &xps[(t & 1) * 16 * XP];
    ushortT* hw = &hbuf[(t % RING) * 16 * HP];
#pragma unroll
    for (int u = 0; u < NU; u++) {
#pragma unroll
      for (int r = 0; r < 4; r++) {
        const int xrow = (lq * 4 + r) * XP;
        const int col = s * SL + u * 16 + lm;
        const float iv = acc[0][u][r] + bf2f(xb[xrow + 0 * H + col]);
        const float fv = acc[1][u][r] + bf2f(xb[xrow + 1 * H + col]);
        const float gg = acc[2][u][r] + bf2f(xb[xrow + 2 * H + col]);
        const float ov = acc[3][u][r] + bf2f(xb[xrow + 3 * H + col]);
        const float ei = __expf(-iv), ef = __expf(-fv), eg = __expf(-2.f * gg);
        const float pi = 1.f + ei, pf = 1.f + ef, pg = 1.f + eg;
        const float cc = (cst[u][r] * pi * pg + (1.f - eg) * pf) *
                         __builtin_amdgcn_rcpf(pf * pi * pg);
        cst[u][r] = cc;
        const float ec = __expf(-2.f * cc), eo = __expf(-ov);
        const float hv = (1.f - ec) * __builtin_amdgcn_rcpf((1.f + eo) * (1.f + ec));
        hw[(lq * 4 + r) * HP + col] = (ushortT)f2bf(hv);
      }
    }
    // ---- commit staged xp for t+1 ----
    {
      uint4* dst = (uint4*)&xps[((t + 1) & 1) * 16 * XP + srow * XP + sch * (C4H / 16)];
#pragma unroll
      for (int i = 0; i < NCH4; i++) dst[i] = sv[i];
    }
    __syncthreads();
  }
  // final flush: z rows 252..255
  {
    const int t0 = 252;
#pragma unroll
    for (int i = 0; i < (64 * CRB) / 256; i++) {
      const int q = i * 256 + tid;
      const int m = q / (4 * CRB), j = (q / CRB) & 3, cr = q % CRB;
      const uint4 v = *(const uint4*)&hbuf[((t0 + j) % RING) * 16 * HP + m * HP + cr * 8];
      *(uint4*)&z[((size_t)(b0 + m) * 256 + t0 + j) * 256 + COFF + cr * 8] = v;
    }
  }
}

__global__ __launch_bounds__(256, 1) void recur2_k(const ushortT* __restrict__ xpt,
                                                   const ushortT* __restrict__ xpa,
                                                   const ushortT* __restrict__ xpv_,
                                                   const ushortT* __restrict__ Wt,
                                                   const ushortT* __restrict__ Wa,
                                                   const ushortT* __restrict__ Wv,
                                                   ushortT* __restrict__ z) {
  extern __shared__ char smem[];
  const int bid = blockIdx.x;
  if (bid < 16) recur_impl2<128, 128>(xpt, Wt, z, bid, smem);
  else if (bid < 32) recur_impl2<64, 0>(xpa, Wa, z, bid - 16, smem);
  else recur_impl2<64, 64>(xpv_, Wv, z, bid - 32, smem);
}

// ------------------------------- fusion ------------------------------------
__global__ __launch_bounds__(192) void fusion_k(const ushortT* __restrict__ z,
                                                const float* __restrict__ W1,
                                                const float* __restrict__ b1,
                                                const float* __restrict__ W2,
                                                const float* __restrict__ b2,
                                                const float* __restrict__ fw,
                                                float* __restrict__ s_acc,
                                                float* __restrict__ sumsq) {
  __shared__ __align__(16) float zs[256 * 36];
  __shared__ float red[8];
  const int tid = threadIdx.x;
  const int b = blockIdx.x >> 3;
  const int t0 = (blockIdx.x & 7) * 32;
  const ushortT* zb = z + (size_t)b * 65536;
  float sq = 0.0f;
  for (int idx = tid; idx < 33 * 256; idx += 192) {
    const int row = idx >> 8, k = idx & 255;
    int t = t0 + row; if (t >= 256) t -= 256;
    const float v = bf2f(zb[t * 256 + k]);
    zs[k * 36 + row] = v;
    if (row < 32) sq += v * v;
  }
  __syncthreads();
  const int dg = tid >> 3;
  const int rg = tid & 7;
  const float* w1p = W1 + dg * 256;
  const float* w2p = W2 + dg * 513;
  float aa[4] = {}, ab1[4] = {}, ab2[4] = {};
#pragma unroll 4
  for (int k = 0; k < 256; k++) {
    const float w1v = w1p[k];
    const float w21 = w2p[1 + k];
    const float w22 = w2p[257 + k];
    const float* zr = &zs[k * 36 + (rg << 2)];
    const float4 za = *(const float4*)zr;
    const float z4 = zr[4];
    aa[0]  += za.x * w1v; aa[1]  += za.y * w1v; aa[2]  += za.z * w1v; aa[3]  += za.w * w1v;
    ab1[0] += za.x * w21; ab1[1] += za.y * w21; ab1[2] += za.z * w21; ab1[3] += za.w * w21;
    ab2[0] += za.y * w22; ab2[1] += za.z * w22; ab2[2] += za.w * w22; ab2[3] += z4   * w22;
  }
  const float b1v = b1[dg];
  const float b2v = b2[dg] + w2p[0];
  const float fwv = fw[dg];
  float s = 0.0f;
#pragma unroll
  for (int i = 0; i < 4; i++) {
    const float a  = aa[i] + b1v;
    const float bb = ab1[i] + ab2[i] + b2v;
    s += a * bb;
  }
  s *= fwv;
#pragma unroll
  for (int off = 32; off > 0; off >>= 1) {
    s  += __shfl_down(s, off);
    sq += __shfl_down(sq, off);
  }
  const int wid = tid >> 6;
  if ((tid & 63) == 0) { red[wid * 2] = s; red[wid * 2 + 1] = sq; }
  __syncthreads();
  if (tid == 0) {
    atomicAdd(&s_acc[b], red[0] + red[2] + red[4]);
    atomicAdd(&sumsq[b], red[1] + red[3] + red[5]);
  }
}

// ------------------------------- epilogue ----------------------------------
__global__ __launch_bounds__(256) void final_k(const float* __restrict__ s_acc,
                                               const float* __restrict__ sumsq,
                                               float* __restrict__ out) {
  __shared__ float red[4];
  const int tid = threadIdx.x;
  out[tid] = s_acc[tid] * (1.0f / 256.0f);
  float sq = sqrtf(sumsq[tid]);
#pragma unroll
  for (int off = 32; off > 0; off >>= 1) sq += __shfl_down(sq, off);
  if ((tid & 63) == 0) red[tid >> 6] = sq;
  __syncthreads();
  if (tid == 0) out[256] = (red[0] + red[1] + red[2] + red[3]) * (1.0f / 256.0f);
}

// ---------------------------------------------------------------------------
extern "C" void kernel_launch(void* const* d_in, const int* in_sizes, int n_in,
                              void* d_out, int out_size, void* d_ws, size_t ws_size,
                              hipStream_t stream) {
  const float* text   = (const float*)d_in[0];
  const float* audio  = (const float*)d_in[1];
  const float* vision = (const float*)d_in[2];
  const float* Wih_t  = (const float*)d_in[3];
  const float* Whh_t  = (const float*)d_in[4];
  const float* b_t    = (const float*)d_in[5];
  const float* Wih_a  = (const float*)d_in[6];
  const float* Whh_a  = (const float*)d_in[7];
  const float* b_a    = (const float*)d_in[8];
  const float* Wih_v  = (const float*)d_in[9];
  const float* Whh_v  = (const float*)d_in[10];
  const float* b_v    = (const float*)d_in[11];
  const float* W1     = (const float*)d_in[12];
  const float* b1     = (const float*)d_in[13];
  const float* W2     = (const float*)d_in[14];
  const float* b2     = (const float*)d_in[15];
  const float* fw     = (const float*)d_in[16];

  // workspace layout (bf16 elems unless noted)
  ushortT* xpt = (ushortT*)d_ws;               // 65536*512
  ushortT* xpa = xpt + (size_t)33554432;       // 65536*256
  ushortT* xpv = xpa + (size_t)16777216;       // 65536*256
  ushortT* z16 = xpv + (size_t)16777216;       // 65536*256
  float* s_acc = (float*)(z16 + (size_t)16777216);  // 256 f32
  float* sumsq = s_acc + 256;                       // 256 f32
  ushortT* WhhT16 = (ushortT*)(sumsq + 256);   // 512*128
  ushortT* WhhA16 = WhhT16 + 65536;            // 256*64
  ushortT* WhhV16 = WhhA16 + 16384;            // 256*64
  // scratch aliased into z16 (fully consumed before recur2_k writes z):
  ushortT* A16a  = z16;                        // 65536*96
  ushortT* A16v  = A16a + (size_t)6291456;     // 65536*64
  ushortT* Wt768 = A16v + (size_t)4194304;     // 512*768
  ushortT* WA16  = Wt768 + 393216;             // 256*96
  ushortT* WV16  = WA16 + 24576;               // 256*64

  hipMemsetAsync(s_acc, 0, 512 * sizeof(float), stream);

  pad_cvt_k<768, 768><<<1536, 256, 0, stream>>>(Wih_t, Wt768, 512 * 768);
  pad_cvt_k<128, 128><<<256, 256, 0, stream>>>(Whh_t, WhhT16, 512 * 128);
  pad_cvt_k<64, 64><<<64, 256, 0, stream>>>(Whh_a, WhhA16, 256 * 64);
  pad_cvt_k<64, 64><<<64, 256, 0, stream>>>(Whh_v, WhhV16, 256 * 64);
  pad_cvt_k<96, 74><<<96, 256, 0, stream>>>(Wih_a, WA16, 256 * 96);
  pad_cvt_k<64, 35><<<64, 256, 0, stream>>>(Wih_v, WV16, 256 * 64);
  pad_cvt_k<96, 74><<<24576, 256, 0, stream>>>(audio, A16a, 65536 * 96);
  pad_cvt_k<64, 35><<<16384, 256, 0, stream>>>(vision, A16v, 65536 * 64);

  gemm_text2_k<<<1024, 512, 0, stream>>>(text, Wt768, b_t, xpt);
  gemm_xp_k<96><<<dim3(2, 512), 256, 0, stream>>>(A16a, WA16, b_a, xpa);
  gemm_xp_k<64><<<dim3(2, 512), 256, 0, stream>>>(A16v, WV16, b_v, xpv);
  // dynamic LDS: text variant needs 6*16*136*2 + 2*16*520*2 = 59392 B
  recur2_k<<<48, 256, 59392, stream>>>(xpt, xpa, xpv, WhhT16, WhhA16, WhhV16, z16);
  fusion_k<<<2048, 192, 0, stream>>>(z16, W1, b1, W2, b2, fw, s_acc, sumsq);
  final_k<<<1, 256, 0, stream>>>(s_acc, sumsq, (float*)d_out);
}